// Round 6
// baseline (110.621 us; speedup 1.0000x reference)
//
#include <hip/hip_runtime.h>
#include <hip/hip_bf16.h>

#define NPART 8192
#define NCT 4
#define TPB 128                             // 2 waves/block, 1 i-row per thread
#define TILE 128                            // i-tile == j-tile size
#define NTILE (NPART / TILE)                // 64
#define NBLK (NTILE * (NTILE + 1) / 2)      // 2080 triangular tiles -> 4160 waves (~4/SIMD)
#define NSLOT 64
#define POISON_U 0xAAAAAAAAu

// ws layout: [0..255] float acc64[64] (poisoned; bias corrected at end), [256] uint cnt (poisoned)

// dtype-generic scalar load: bf16 (upcast, exact) or fp32
__device__ __forceinline__ float loadf(const void* p, int idx, bool bf) {
    if (bf) {
        unsigned int u = ((const unsigned short*)p)[idx];
        return __uint_as_float(u << 16);
    }
    return ((const float*)p)[idx];
}

__device__ __forceinline__ int spec_of(const void* ct, int i, bool bf) {
    int s = -1;
#pragma unroll
    for (int c = 0; c < NCT; ++c)
        if (loadf(ct, i * NCT + c, bf) > 0.5f) s = c;
    return s;
}

__global__ __launch_bounds__(TPB) void morse_kernel(const void* __restrict__ eps,
                                                    const void* __restrict__ alp,
                                                    const void* __restrict__ ct,
                                                    const void* __restrict__ rad,
                                                    const void* __restrict__ pos,
                                                    float* __restrict__ acc64,
                                                    unsigned int* __restrict__ cnt,
                                                    void* __restrict__ out)
{
    __shared__ float4 sp[TILE];
    __shared__ int ssp[TILE];
    __shared__ float stab[32];
    __shared__ float red[TPB / 64];

    const int t = threadIdx.x;

    // dtype detection (wave-uniform): fp32 one-hot words always have low16 == 0
    unsigned int w = ((const unsigned int*)ct)[t & 63];
    const bool bf = (__ballot((w & 0xFFFFu) != 0) != 0ull);

    // triangular tile decode: linear b -> (bx <= by)
    const int b = blockIdx.x;
    int by = (int)((sqrtf(8.0f * (float)b + 1.0f) - 1.0f) * 0.5f);
    while ((by + 1) * (by + 2) / 2 <= b) ++by;
    while (by * (by + 1) / 2 > b) --by;
    const int bx = b - by * (by + 1) / 2;
    const bool diag = (bx == by);

    // species tables: symmetrize + sigmoid*vmax + vmin
    if (t < 16) {
        int a = t >> 2, c = t & 3;
        float me = (a == c) ? loadf(eps, a * NCT + a, bf)
                            : 0.5f * (loadf(eps, a * NCT + c, bf) + loadf(eps, c * NCT + a, bf));
        float ma = (a == c) ? loadf(alp, a * NCT + a, bf)
                            : 0.5f * (loadf(alp, a * NCT + c, bf) + loadf(alp, c * NCT + a, bf));
        stab[t]      = 5.0f / (1.0f + __expf(-me)) + 1.0f;   // EPS range
        stab[16 + t] = 3.0f / (1.0f + __expf(-ma)) + 1.0f;   // ALPHA range
    }

    // stage j-tile (1 per thread)
    const int j0 = by * TILE;
    {
        int j = j0 + t;
        float4 pj;
        pj.x = loadf(pos, j * 3 + 0, bf);
        pj.y = loadf(pos, j * 3 + 1, bf);
        pj.z = loadf(pos, j * 3 + 2, bf);
        pj.w = loadf(rad, j, bf);
        sp[t] = pj;
        ssp[t] = spec_of(ct, j, bf);
    }

    // own i row
    const int i = bx * TILE + t;
    float4 pi;
    pi.x = loadf(pos, i * 3 + 0, bf);
    pi.y = loadf(pos, i * 3 + 1, bf);
    pi.z = loadf(pos, i * 3 + 2, bf);
    pi.w = loadf(rad, i, bf);
    const int si = spec_of(ct, i, bf);

    __syncthreads();

    constexpr float RC2 = 4.0f;            // R_CUTOFF^2
    constexpr float RO2 = 1.7f * 1.7f;     // R_ONSET^2
    constexpr float C1  = RC2 - 3.0f * RO2;
    const float INV_D = 1.0f / ((RC2 - RO2) * (RC2 - RO2) * (RC2 - RO2));

    float acc = 0.0f;
    if (si >= 0) {
#pragma unroll 8
        for (int jj = 0; jj < TILE; ++jj) {
            float4 pj = sp[jj];             // broadcast ds_read_b128 (proven ~14 cyc/iter body)
            float dx = pi.x - pj.x;
            float dy = pi.y - pj.y;
            float dz = pi.z - pj.z;
            float dr2 = fmaf(dx, dx, fmaf(dy, dy, dz * dz));
            if (dr2 < RC2) {                // rare hit (~0.05% of pairs)
                int j = j0 + jj;
                int sj = ssp[jj];
                if (j != i && sj >= 0) {
                    float e = stab[(si << 2) | sj];
                    float a = stab[16 + ((si << 2) | sj)];
                    float dr = sqrtf(dr2);
                    float ex = __expf(-a * (dr - (pi.w + pj.w)));
                    float om = 1.0f - ex;
                    float u = fmaf(e * om, om, -e);          // eps*(1-ex)^2 - eps
                    float smooth = 1.0f;
                    if (dr2 >= RO2) {
                        float d = RC2 - dr2;
                        smooth = d * d * fmaf(2.0f, dr2, C1) * INV_D;
                    }
                    acc += u * smooth;
                }
            }
        }
    }

    // off-diag tiles cover each unordered pair once; diag tiles 0.5 * sum_{i!=j}
    acc *= diag ? 0.5f : 1.0f;

    // wave(64) shuffle reduction -> LDS -> block sum
#pragma unroll
    for (int off = 32; off > 0; off >>= 1) acc += __shfl_down(acc, off, 64);
    if ((t & 63) == 0) red[t >> 6] = acc;
    __syncthreads();

    // one spread-slot atomic per block; device-scope atomics only across XCDs
    int lastv = 0;
    if (t == 0) {
        atomicAdd(&acc64[b & (NSLOT - 1)], red[0] + red[1]);
        __threadfence();
        unsigned int old = atomicAdd(cnt, 1u);              // cnt starts at poison
        lastv = (old == POISON_U + (NBLK - 1)) ? 1 : 0;
    }
    if (t < 64) {
        int lastw = __shfl(lastv, 0, 64);                   // broadcast within wave 0
        if (lastw) {                                        // last block: fused finalize
            __threadfence();
            // coherent read of each slot; remove the poison bias each slot started with
            float v = atomicAdd(&acc64[t], 0.0f) - __uint_as_float(POISON_U);
#pragma unroll
            for (int off = 32; off > 0; off >>= 1) v += __shfl_down(v, off, 64);
            if (t == 0) {
                if (bf) ((__hip_bfloat16*)out)[0] = __float2bfloat16(v);
                else    ((float*)out)[0] = v;
            }
        }
    }
}

extern "C" void kernel_launch(void* const* d_in, const int* in_sizes, int n_in,
                              void* d_out, int out_size, void* d_ws, size_t ws_size,
                              hipStream_t stream)
{
    // Map inputs by element count (robust to ordering); eps/alpha both 16 -> keep order.
    const void* eps = nullptr; const void* alp = nullptr;
    const void* ct = nullptr;  const void* rad = nullptr; const void* pos = nullptr;
    int nsmall = 0;
    for (int k = 0; k < n_in; ++k) {
        int s = in_sizes[k];
        if (s == NCT * NCT)        { if (nsmall++ == 0) eps = d_in[k]; else alp = d_in[k]; }
        else if (s == NPART * NCT) ct  = d_in[k];
        else if (s == NPART)       rad = d_in[k];
        else if (s == NPART * 3)   pos = d_in[k];
    }
    if (!eps || !alp || !ct || !rad || !pos) {
        eps = d_in[0]; alp = d_in[1]; ct = d_in[2]; rad = d_in[3]; pos = d_in[4];
    }

    float*        acc64 = (float*)d_ws;                    // 64 slots, poison-biased
    unsigned int* cnt   = (unsigned int*)((char*)d_ws + 256);

    morse_kernel<<<NBLK, TPB, 0, stream>>>(eps, alp, ct, rad, pos, acc64, cnt, d_out);
}

// Round 7
// 89.305 us; speedup vs baseline: 1.2387x; 1.2387x over previous
//
#include <hip/hip_runtime.h>
#include <hip/hip_bf16.h>

#define NPART 8192
#define NCT 4
#define TPB 256                             // 4 waves/block, 1 i-row per thread
#define TILE 256                            // i-tile == j-tile size
#define NTILE (NPART / TILE)                // 32
#define NBLK (NTILE * (NTILE + 1) / 2)      // 528 triangular tiles
#define NSLOT 64
#define POISON_U 0xAAAAAAAAu

// ws layout: [0..255] float acc64[64] (poison-biased), [256] uint cnt (poisoned)

// dtype-generic scalar load: bf16 (upcast, exact) or fp32
__device__ __forceinline__ float loadf(const void* p, int idx, bool bf) {
    if (bf) {
        unsigned int u = ((const unsigned short*)p)[idx];
        return __uint_as_float(u << 16);
    }
    return ((const float*)p)[idx];
}

__device__ __forceinline__ int spec_of(const void* ct, int i, bool bf) {
    int s = -1;
#pragma unroll
    for (int c = 0; c < NCT; ++c)
        if (loadf(ct, i * NCT + c, bf) > 0.5f) s = c;
    return s;
}

// broadcast lane l's float across the wave via v_readlane (no LDS latency)
__device__ __forceinline__ float rdlane(float v, int l) {
    return __uint_as_float((unsigned int)__builtin_amdgcn_readlane((int)__float_as_uint(v), l));
}

__global__ __launch_bounds__(TPB) void morse_kernel(const void* __restrict__ eps,
                                                    const void* __restrict__ alp,
                                                    const void* __restrict__ ct,
                                                    const void* __restrict__ rad,
                                                    const void* __restrict__ pos,
                                                    float* __restrict__ acc64,
                                                    unsigned int* __restrict__ cnt,
                                                    void* __restrict__ out)
{
    __shared__ float4 sp[TILE];
    __shared__ int ssp[TILE];
    __shared__ float stab[32];
    __shared__ float red[TPB / 64];

    const int t = threadIdx.x;
    const int lane = t & 63;

    // dtype detection (wave-uniform): fp32 one-hot words always have low16 == 0
    unsigned int wdet = ((const unsigned int*)ct)[t & 63];
    const bool bf = (__ballot((wdet & 0xFFFFu) != 0) != 0ull);

    // triangular tile decode: linear b -> (bx <= by)
    const int b = blockIdx.x;
    int by = (int)((sqrtf(8.0f * (float)b + 1.0f) - 1.0f) * 0.5f);
    while ((by + 1) * (by + 2) / 2 <= b) ++by;
    while (by * (by + 1) / 2 > b) --by;
    const int bx = b - by * (by + 1) / 2;
    const bool diag = (bx == by);

    // species tables: symmetrize + sigmoid*vmax + vmin
    if (t < 16) {
        int a = t >> 2, c = t & 3;
        float me = (a == c) ? loadf(eps, a * NCT + a, bf)
                            : 0.5f * (loadf(eps, a * NCT + c, bf) + loadf(eps, c * NCT + a, bf));
        float ma = (a == c) ? loadf(alp, a * NCT + a, bf)
                            : 0.5f * (loadf(alp, a * NCT + c, bf) + loadf(alp, c * NCT + a, bf));
        stab[t]      = 5.0f / (1.0f + __expf(-me)) + 1.0f;   // EPS range
        stab[16 + t] = 3.0f / (1.0f + __expf(-ma)) + 1.0f;   // ALPHA range
    }

    // stage j-tile (1 per thread)
    const int j0 = by * TILE;
    {
        int j = j0 + t;
        float4 pj;
        pj.x = loadf(pos, j * 3 + 0, bf);
        pj.y = loadf(pos, j * 3 + 1, bf);
        pj.z = loadf(pos, j * 3 + 2, bf);
        pj.w = loadf(rad, j, bf);
        sp[t] = pj;
        ssp[t] = spec_of(ct, j, bf);
    }

    // own i row
    const int i = bx * TILE + t;
    float4 pi;
    pi.x = loadf(pos, i * 3 + 0, bf);
    pi.y = loadf(pos, i * 3 + 1, bf);
    pi.z = loadf(pos, i * 3 + 2, bf);
    pi.w = loadf(rad, i, bf);
    const int si = spec_of(ct, i, bf);

    __syncthreads();

    constexpr float RC2 = 4.0f;            // R_CUTOFF^2
    constexpr float RO2 = 1.7f * 1.7f;     // R_ONSET^2
    constexpr float C1  = RC2 - 3.0f * RO2;
    const float INV_D = 1.0f / ((RC2 - RO2) * (RC2 - RO2) * (RC2 - RO2));

    float acc = 0.0f;
    // j-tile swept in 64-particle chunks held in the wave's registers;
    // inner broadcast via v_readlane -> no memory op in the dependent chain.
    for (int c = 0; c < TILE / 64; ++c) {
        float4 jreg = sp[c * 64 + lane];   // per-lane 16B, 2-way bank alias (free)
        int    jsreg = ssp[c * 64 + lane];
        for (int c2 = 0; c2 < 4; ++c2) {   // 4 x unroll16 keeps code ~6KB
#pragma unroll
            for (int k = 0; k < 16; ++k) {
                const int l = c2 * 16 + k;             // wave-uniform lane index
                float xj = rdlane(jreg.x, l);
                float yj = rdlane(jreg.y, l);
                float zj = rdlane(jreg.z, l);
                float dx = pi.x - xj;
                float dy = pi.y - yj;
                float dz = pi.z - zj;
                float dr2 = fmaf(dx, dx, fmaf(dy, dy, dz * dz));
                if (dr2 < RC2) {                        // rare hit
                    int j = j0 + c * 64 + l;
                    int sj = __builtin_amdgcn_readlane(jsreg, l);
                    float rj = rdlane(jreg.w, l);
                    if (j != i && sj >= 0 && si >= 0) {
                        float e = stab[(si << 2) | sj];
                        float a = stab[16 + ((si << 2) | sj)];
                        float dr = sqrtf(dr2);
                        float ex = __expf(-a * (dr - (pi.w + rj)));
                        float om = 1.0f - ex;
                        float u = fmaf(e * om, om, -e);  // eps*(1-ex)^2 - eps
                        float smooth = 1.0f;
                        if (dr2 >= RO2) {
                            float d = RC2 - dr2;
                            smooth = d * d * fmaf(2.0f, dr2, C1) * INV_D;
                        }
                        acc += u * smooth;
                    }
                }
            }
        }
    }

    // off-diag tiles cover each unordered pair once; diag tiles 0.5 * sum_{i!=j}
    acc *= diag ? 0.5f : 1.0f;

    // wave(64) shuffle reduction -> LDS -> block sum
#pragma unroll
    for (int off = 32; off > 0; off >>= 1) acc += __shfl_down(acc, off, 64);
    if ((t & 63) == 0) red[t >> 6] = acc;
    __syncthreads();

    // one spread-slot atomic per block; device-scope atomics only across XCDs
    int lastv = 0;
    if (t == 0) {
        atomicAdd(&acc64[b & (NSLOT - 1)], red[0] + red[1] + red[2] + red[3]);
        __threadfence();
        unsigned int old = atomicAdd(cnt, 1u);              // cnt starts at poison
        lastv = (old == POISON_U + (NBLK - 1)) ? 1 : 0;
    }
    if (t < 64) {
        int lastw = __shfl(lastv, 0, 64);                   // broadcast within wave 0
        if (lastw) {                                        // last block: fused finalize
            __threadfence();
            float v = atomicAdd(&acc64[t], 0.0f) - __uint_as_float(POISON_U);
#pragma unroll
            for (int off = 32; off > 0; off >>= 1) v += __shfl_down(v, off, 64);
            if (t == 0) {
                if (bf) ((__hip_bfloat16*)out)[0] = __float2bfloat16(v);
                else    ((float*)out)[0] = v;
            }
        }
    }
}

extern "C" void kernel_launch(void* const* d_in, const int* in_sizes, int n_in,
                              void* d_out, int out_size, void* d_ws, size_t ws_size,
                              hipStream_t stream)
{
    // Map inputs by element count (robust to ordering); eps/alpha both 16 -> keep order.
    const void* eps = nullptr; const void* alp = nullptr;
    const void* ct = nullptr;  const void* rad = nullptr; const void* pos = nullptr;
    int nsmall = 0;
    for (int k = 0; k < n_in; ++k) {
        int s = in_sizes[k];
        if (s == NCT * NCT)        { if (nsmall++ == 0) eps = d_in[k]; else alp = d_in[k]; }
        else if (s == NPART * NCT) ct  = d_in[k];
        else if (s == NPART)       rad = d_in[k];
        else if (s == NPART * 3)   pos = d_in[k];
    }
    if (!eps || !alp || !ct || !rad || !pos) {
        eps = d_in[0]; alp = d_in[1]; ct = d_in[2]; rad = d_in[3]; pos = d_in[4];
    }

    float*        acc64 = (float*)d_ws;                    // 64 slots, poison-biased
    unsigned int* cnt   = (unsigned int*)((char*)d_ws + 256);

    morse_kernel<<<NBLK, TPB, 0, stream>>>(eps, alp, ct, rad, pos, acc64, cnt, d_out);
}